// Round 5
// baseline (130.651 us; speedup 1.0000x reference)
//
#include <hip/hip_runtime.h>
#include <hip/hip_bf16.h>
#include <cstdint>

// Setformer:  B=8192 sets, S=64 max rows, D=H=O=128.
// Algebraic reduction (exact):
//   pooled[b] = omega @ X @ (Wv Wo) + (bv Wo + bo),
//   omega[t]  = (1/L) * sum_{s<L} softmax_t( G[s] . x_t ),
//   G         = (X @ (Wq Wk^T) + (Wk bq)) / sqrt(D)        (bk cancels in softmax)
// R5: back to 1 set/block (R3 structure). Changes vs R3:
//   - no min-waves clause in __launch_bounds__ (R2-R4's (512,6) capped VGPR<=85;
//     suspected scratch spills in MFMA/softmax phases)
//   - staging loads fully hoisted: 4 predicated float4 loads issued
//     back-to-back -> one HBM round-trip instead of up to 4 serialized
//   - main kernel launched TWICE (deterministic, identical writes) so
//     T_main can be extracted by subtraction next round. dur_us this
//     round = overhead + 2*T_main, intentionally inflated.

typedef __attribute__((ext_vector_type(8))) short bf16x8;
typedef __attribute__((ext_vector_type(4))) float f32x4;

__device__ __forceinline__ unsigned short f2bf(float f) {
    unsigned int u = __builtin_bit_cast(unsigned int, f);
    u += 0x7fffu + ((u >> 16) & 1u);           // round-to-nearest-even
    return (unsigned short)(u >> 16);
}
__device__ __forceinline__ float bf2f(unsigned short s) {
    unsigned int u = ((unsigned int)s) << 16;
    return __builtin_bit_cast(float, u);
}
__device__ __forceinline__ unsigned cvt_pk_bf16(float lo, float hi) {
    unsigned r;
    asm("v_cvt_pk_bf16_f32 %0, %1, %2" : "=v"(r) : "v"(lo), "v"(hi));
    return r;
}

// Precompute (tiny):
//   MtBf[d][e] = (1/sqrt(D)) * sum_h Wq[e][h]*Wk[d][h]   bf16 row-major 128x128 (= M^T, pre-scaled)
//   Nmat[d][o] = sum_h Wv[d][h]*Wo[h][o]                 fp32
//   wsv[d]     = (1/sqrt(D)) * sum_h Wk[d][h]*bq[h]
//   cvec[o]    = sum_h bv[h]*Wo[h][o] + bo[o]
__global__ __launch_bounds__(256) void setformer_pre(
    const float* __restrict__ Wq, const float* __restrict__ Wk,
    const float* __restrict__ Wv, const float* __restrict__ Wo,
    const float* __restrict__ bq, const float* __restrict__ bv,
    const float* __restrict__ bo,
    unsigned short* __restrict__ MtBf, float* __restrict__ Nmat,
    float* __restrict__ wsv, float* __restrict__ cvec)
{
    __shared__ float sKd[128], sVd[128];
    const int d = blockIdx.x, tid = threadIdx.x;
    if (tid < 128) { sKd[tid] = Wk[d*128 + tid]; sVd[tid] = Wv[d*128 + tid]; }
    __syncthreads();
    const float invs = 0.088388347648318447f;  // 1/sqrt(128)
    if (tid < 128) {
        const int e = tid;
        float acc = 0.f;
        for (int h = 0; h < 128; ++h) acc = fmaf(Wq[e*128 + h], sKd[h], acc);
        MtBf[d*128 + e] = f2bf(acc * invs);
    } else {
        const int o = tid - 128;
        float acc = 0.f;
        for (int h = 0; h < 128; ++h) acc = fmaf(sVd[h], Wo[h*128 + o], acc);
        Nmat[d*128 + o] = acc;
    }
    if (d == 0 && tid < 128) {
        float a = 0.f, c = 0.f;
        for (int h = 0; h < 128; ++h) {
            a = fmaf(Wk[tid*128 + h], bq[h], a);
            c = fmaf(bv[h], Wo[h*128 + tid], c);
        }
        wsv[tid]  = a * invs;
        cvec[tid] = c + bo[tid];
    }
}

// Main: one block (512 thr = 8 waves) per set; outputs y[b,:] = omega @ X.
__global__ __launch_bounds__(512) void setformer_main(
    const float* __restrict__ neigh, const int* __restrict__ lengths,
    const unsigned short* __restrict__ MtBf,
    const float* __restrict__ wsv, float* __restrict__ yout)
{
    __shared__ unsigned short sX[64 * 128];   // bf16, XOR-swizzled (byte ^= (row&7)<<4)
    __shared__ unsigned short sG[64 * 128];   // bf16, same swizzle
    __shared__ float sWp[4][64];              // per-s-tile column-sum partials (omega parts)
    __shared__ float sW[64];                  // omega
    __shared__ float sY4[4][128];             // y partials over t-quarters

    const int tid  = threadIdx.x;
    const int lane = tid & 63;
    const int wv   = tid >> 6;    // wave 0..7
    const int l15  = lane & 15;
    const int lg   = lane >> 4;   // 0..3
    const int b    = blockIdx.x;

    // ---- Prefetch M B-fragments (tile dt=wv) + wadd (L2-hot, independent). ----
    const char* bB = (const char*)MtBf + (wv*16 + l15) * 256;
    bf16x8 bfr0 = *(const bf16x8*)(bB +   0 + lg*16);
    bf16x8 bfr1 = *(const bf16x8*)(bB +  64 + lg*16);
    bf16x8 bfr2 = *(const bf16x8*)(bB + 128 + lg*16);
    bf16x8 bfr3 = *(const bf16x8*)(bB + 192 + lg*16);
    const float wadd = wsv[wv*16 + l15];

    // ---- Staging: row 0-15 load issues before lengths; rows 16-63 issue
    //      back-to-back right after L arrives (one exposed round-trip).
    const float4* np4 = (const float4*)(neigh + (size_t)b * 8192);
    const float4 f0 = np4[tid];               // rows 0..15, always maybe-needed

    int L = lengths[b];
    L = max(1, min(64, L));
    const int ST = (L + 15) >> 4;             // 16-row tiles actually needed
    const int rr = tid >> 5, c4 = tid & 31;   // rr in 0..15

    float4 f1 = {0,0,0,0}, f2 = {0,0,0,0}, f3 = {0,0,0,0};
    if (rr + 16 < L) f1 = np4[tid + 512];     // all three issued together
    if (rr + 32 < L) f2 = np4[tid + 1024];
    if (rr + 48 < L) f3 = np4[tid + 1536];

    if (tid < 256) ((float*)sWp)[tid] = 0.f;

    {
        uint2 v = {0u, 0u};
        if (rr < L) { v.x = cvt_pk_bf16(f0.x, f0.y); v.y = cvt_pk_bf16(f0.z, f0.w); }
        *(uint2*)((char*)sX + rr*256 + ((c4*8) ^ ((rr & 7) << 4))) = v;
        if (ST > 1) {
            const int r = rr + 16;
            uint2 w = {0u, 0u};
            if (r < L) { w.x = cvt_pk_bf16(f1.x, f1.y); w.y = cvt_pk_bf16(f1.z, f1.w); }
            *(uint2*)((char*)sX + r*256 + ((c4*8) ^ ((r & 7) << 4))) = w;
        }
        if (ST > 2) {
            const int r = rr + 32;
            uint2 w = {0u, 0u};
            if (r < L) { w.x = cvt_pk_bf16(f2.x, f2.y); w.y = cvt_pk_bf16(f2.z, f2.w); }
            *(uint2*)((char*)sX + r*256 + ((c4*8) ^ ((r & 7) << 4))) = w;
        }
        if (ST > 3) {
            const int r = rr + 48;
            uint2 w = {0u, 0u};
            if (r < L) { w.x = cvt_pk_bf16(f3.x, f3.y); w.y = cvt_pk_bf16(f3.z, f3.w); }
            *(uint2*)((char*)sX + r*256 + ((c4*8) ^ ((r & 7) << 4))) = w;
        }
    }
    __syncthreads();

    // ---- Phase 2: G(:, dt=wv) = X @ M(:, wv-tile) + w, bf16 into sG ----
    for (int st = 0; st < ST; ++st) {
        const char* aB = (const char*)sX + (st*16 + l15) * 256;
        f32x4 acc = {0.f, 0.f, 0.f, 0.f};
        bf16x8 a0 = *(const bf16x8*)(aB + ((  0 + lg*16) ^ ((l15 & 7) << 4)));
        acc = __builtin_amdgcn_mfma_f32_16x16x32_bf16(a0, bfr0, acc, 0, 0, 0);
        bf16x8 a1 = *(const bf16x8*)(aB + (( 64 + lg*16) ^ ((l15 & 7) << 4)));
        acc = __builtin_amdgcn_mfma_f32_16x16x32_bf16(a1, bfr1, acc, 0, 0, 0);
        bf16x8 a2 = *(const bf16x8*)(aB + ((128 + lg*16) ^ ((l15 & 7) << 4)));
        acc = __builtin_amdgcn_mfma_f32_16x16x32_bf16(a2, bfr2, acc, 0, 0, 0);
        bf16x8 a3 = *(const bf16x8*)(aB + ((192 + lg*16) ^ ((l15 & 7) << 4)));
        acc = __builtin_amdgcn_mfma_f32_16x16x32_bf16(a3, bfr3, acc, 0, 0, 0);
        // D layout: row = lg*4+j, col = l15  (m89-verified)
        #pragma unroll
        for (int j = 0; j < 4; ++j) {
            const int gr  = st*16 + lg*4 + j;
            const int gcb = ((wv*16 + l15) * 2) ^ ((gr & 7) << 4);
            const float g = acc[j] + wadd;
            *(unsigned short*)((char*)sG + gr*256 + gcb) =
                (unsigned short)cvt_pk_bf16(g, g);
        }
    }
    __syncthreads();

    // ---- Phase 3: scores = G @ X^T, no-max softmax (scores ~N(0,1): global
    //      max ~5.5 sigma << fp32 exp overflow), column sums -> omega parts ----
    if (wv < ST) {
        const char* aB = (const char*)sG + (wv*16 + l15) * 256;
        bf16x8 afr[4];
        #pragma unroll
        for (int kk = 0; kk < 4; ++kk)
            afr[kk] = *(const bf16x8*)(aB + ((kk*64 + lg*16) ^ ((l15 & 7) << 4)));

        f32x4 sc[4];
        #pragma unroll
        for (int tt = 0; tt < 4; ++tt) {
            f32x4 acc = {0.f, 0.f, 0.f, 0.f};
            if (tt < ST) {
                const char* bBt = (const char*)sX + (tt*16 + l15) * 256;
                #pragma unroll
                for (int kk = 0; kk < 4; ++kk) {
                    bf16x8 bfr = *(const bf16x8*)(bBt + ((kk*64 + lg*16) ^ ((l15 & 7) << 4)));
                    acc = __builtin_amdgcn_mfma_f32_16x16x32_bf16(afr[kk], bfr, acc, 0, 0, 0);
                }
            }
            sc[tt] = acc;
        }

        // rows handled by this lane: s = wv*16 + lg*4 + j ; cols: t = tt*16 + l15
        float den[4] = {0.f, 0.f, 0.f, 0.f};
        #pragma unroll
        for (int tt = 0; tt < 4; ++tt) {
            if (tt < ST) {
                const bool tv = (tt*16 + l15) < L;
                #pragma unroll
                for (int j = 0; j < 4; ++j) {
                    float p = tv ? __expf(sc[tt][j]) : 0.f;
                    sc[tt][j] = p;
                    den[j] += p;
                }
            }
        }
        #pragma unroll
        for (int j = 0; j < 4; ++j) {
            #pragma unroll
            for (int off = 1; off < 16; off <<= 1)
                den[j] += __shfl_xor(den[j], off);
        }
        const float invL = 1.0f / (float)L;
        float rinv[4];
        #pragma unroll
        for (int j = 0; j < 4; ++j) {
            const int srow = wv*16 + lg*4 + j;
            rinv[j] = (srow < L) ? (invL / den[j]) : 0.f;   // 1/L folded -> omega directly
        }
        #pragma unroll
        for (int tt = 0; tt < 4; ++tt) {
            if (tt < ST) {
                float cp = sc[tt][0]*rinv[0] + sc[tt][1]*rinv[1]
                         + sc[tt][2]*rinv[2] + sc[tt][3]*rinv[3];
                cp += __shfl_xor(cp, 16);
                cp += __shfl_xor(cp, 32);
                if (lane < 16) sWp[wv][tt*16 + lane] = cp;
            }
        }
    }
    __syncthreads();

    // ---- omega -> sW ----
    if (tid < 64)
        sW[tid] = sWp[0][tid] + sWp[1][tid] + sWp[2][tid] + sWp[3][tid];
    __syncthreads();

    // ---- y = omega @ X, split 4-way over t across 512 threads ----
    {
        const int q = tid >> 7, col = tid & 127;
        float acc = 0.f;
        const int t0 = q * 16, t1 = min(t0 + 16, L);
        for (int t = t0; t < t1; ++t) {
            const unsigned short xv = *(const unsigned short*)
                ((const char*)sX + t*256 + ((col*2) ^ ((t & 7) << 4)));
            acc = fmaf(sW[t], bf2f(xv), acc);
        }
        sY4[q][col] = acc;
    }
    __syncthreads();

    if (tid < 128)
        yout[(size_t)b*128 + tid] = sY4[0][tid] + sY4[1][tid]
                                  + sY4[2][tid] + sY4[3][tid];
}

// out = Y @ N + c : batched 16-row GEMM; N read once per 16 sets (32MB L2 total).
__global__ __launch_bounds__(256) void setformer_out(
    const float* __restrict__ yin, const float* __restrict__ Nmat,
    const float* __restrict__ cvec, float* __restrict__ out)
{
    __shared__ float sy[16 * 128];
    const int tid = threadIdx.x;
    const size_t r0 = (size_t)blockIdx.x * 16;
    const float4* y4 = (const float4*)(yin + r0 * 128);
    float4* sy4 = (float4*)sy;
    sy4[tid]       = y4[tid];
    sy4[tid + 256] = y4[tid + 256];
    __syncthreads();
    const int col = tid & 127;
    const int rg  = (tid >> 7) * 8;           // rows rg..rg+7 of this 16-row tile
    float acc[8];
    #pragma unroll
    for (int i = 0; i < 8; ++i) acc[i] = 0.f;
    for (int d = 0; d < 128; d += 2) {
        const float n0 = Nmat[(d+0)*128 + col];
        const float n1 = Nmat[(d+1)*128 + col];
        #pragma unroll
        for (int i = 0; i < 8; ++i) {
            const float2 yv = *(const float2*)&sy[(rg + i)*128 + d];  // LDS broadcast
            acc[i] = fmaf(yv.x, n0, acc[i]);
            acc[i] = fmaf(yv.y, n1, acc[i]);
        }
    }
    const float c = cvec[col];
    #pragma unroll
    for (int i = 0; i < 8; ++i)
        out[(r0 + rg + i)*128 + col] = acc[i] + c;
}

extern "C" void kernel_launch(void* const* d_in, const int* in_sizes, int n_in,
                              void* d_out, int out_size, void* d_ws, size_t ws_size,
                              hipStream_t stream)
{
    const float* neigh   = (const float*)d_in[0];
    const int*   lengths = (const int*)  d_in[1];
    const float* Wq = (const float*)d_in[2];
    const float* bq = (const float*)d_in[3];
    const float* Wk = (const float*)d_in[4];
    // d_in[5] = bk: cancels in softmax (row-constant) -- unused.
    const float* Wv = (const float*)d_in[6];
    const float* bv = (const float*)d_in[7];
    const float* Wo = (const float*)d_in[8];
    const float* bo = (const float*)d_in[9];

    const int B = in_sizes[1];   // 8192

    char* ws = (char*)d_ws;
    unsigned short* MtBf = (unsigned short*)(ws);                 // 32768 B
    float* Nmat = (float*)(ws + 32768);                           // 65536 B
    float* wsv  = (float*)(ws + 32768 + 65536);                   // 512 B
    float* cvec = (float*)(ws + 32768 + 65536 + 512);             // 512 B
    float* ybuf = (float*)(ws + 32768 + 65536 + 1024);            // B*128*4 B

    hipLaunchKernelGGL(setformer_pre, dim3(128), dim3(256), 0, stream,
                       Wq, Wk, Wv, Wo, bq, bv, bo, MtBf, Nmat, wsv, cvec);
    // Launched TWICE (deterministic, identical output) -- instrumentation:
    // dur_us = overhead + 2*T_main; next round's single launch isolates T_main.
    hipLaunchKernelGGL(setformer_main, dim3(B), dim3(512), 0, stream,
                       neigh, lengths, MtBf, wsv, ybuf);
    hipLaunchKernelGGL(setformer_main, dim3(B), dim3(512), 0, stream,
                       neigh, lengths, MtBf, wsv, ybuf);
    hipLaunchKernelGGL(setformer_out, dim3(B / 16), dim3(256), 0, stream,
                       ybuf, Nmat, cvec, (float*)d_out);
}

// Round 6
// 77.539 us; speedup vs baseline: 1.6850x; 1.6850x over previous
//
#include <hip/hip_runtime.h>
#include <hip/hip_bf16.h>
#include <cstdint>

// Setformer:  B=8192 sets, S=64 max rows, D=H=O=128.
// Algebraic reduction (exact):
//   pooled[b] = omega @ X @ (Wv Wo) + (bv Wo + bo),
//   omega[t]  = (1/L) * sum_{s<L} softmax_t( G[s] . x_t ),
//   G         = (X @ (Wq Wk^T) + (Wk bq)) / sqrt(D)        (bk cancels in softmax)
// R6 vs R5: __launch_bounds__(512,8) -> VGPR<=64 -> 8 waves/SIMD -> 4 blocks/CU
// (LDS 35.3KB also allows 4; hardware-max 32 waves/CU). Register live ranges
// are phase-local (bfr dead after phase 2, staging regs dead after LDS store,
// phase-3 peak ~60) so the cap should not spill. Single main launch again.

typedef __attribute__((ext_vector_type(8))) short bf16x8;
typedef __attribute__((ext_vector_type(4))) float f32x4;

__device__ __forceinline__ unsigned short f2bf(float f) {
    unsigned int u = __builtin_bit_cast(unsigned int, f);
    u += 0x7fffu + ((u >> 16) & 1u);           // round-to-nearest-even
    return (unsigned short)(u >> 16);
}
__device__ __forceinline__ float bf2f(unsigned short s) {
    unsigned int u = ((unsigned int)s) << 16;
    return __builtin_bit_cast(float, u);
}
__device__ __forceinline__ unsigned cvt_pk_bf16(float lo, float hi) {
    unsigned r;
    asm("v_cvt_pk_bf16_f32 %0, %1, %2" : "=v"(r) : "v"(lo), "v"(hi));
    return r;
}

// Precompute (tiny):
//   MtBf[d][e] = (1/sqrt(D)) * sum_h Wq[e][h]*Wk[d][h]   bf16 row-major 128x128 (= M^T, pre-scaled)
//   Nmat[d][o] = sum_h Wv[d][h]*Wo[h][o]                 fp32
//   wsv[d]     = (1/sqrt(D)) * sum_h Wk[d][h]*bq[h]
//   cvec[o]    = sum_h bv[h]*Wo[h][o] + bo[o]
__global__ __launch_bounds__(256) void setformer_pre(
    const float* __restrict__ Wq, const float* __restrict__ Wk,
    const float* __restrict__ Wv, const float* __restrict__ Wo,
    const float* __restrict__ bq, const float* __restrict__ bv,
    const float* __restrict__ bo,
    unsigned short* __restrict__ MtBf, float* __restrict__ Nmat,
    float* __restrict__ wsv, float* __restrict__ cvec)
{
    __shared__ float sKd[128], sVd[128];
    const int d = blockIdx.x, tid = threadIdx.x;
    if (tid < 128) { sKd[tid] = Wk[d*128 + tid]; sVd[tid] = Wv[d*128 + tid]; }
    __syncthreads();
    const float invs = 0.088388347648318447f;  // 1/sqrt(128)
    if (tid < 128) {
        const int e = tid;
        float acc = 0.f;
        for (int h = 0; h < 128; ++h) acc = fmaf(Wq[e*128 + h], sKd[h], acc);
        MtBf[d*128 + e] = f2bf(acc * invs);
    } else {
        const int o = tid - 128;
        float acc = 0.f;
        for (int h = 0; h < 128; ++h) acc = fmaf(sVd[h], Wo[h*128 + o], acc);
        Nmat[d*128 + o] = acc;
    }
    if (d == 0 && tid < 128) {
        float a = 0.f, c = 0.f;
        for (int h = 0; h < 128; ++h) {
            a = fmaf(Wk[tid*128 + h], bq[h], a);
            c = fmaf(bv[h], Wo[h*128 + tid], c);
        }
        wsv[tid]  = a * invs;
        cvec[tid] = c + bo[tid];
    }
}

// Main: one block (512 thr = 8 waves) per set; outputs y[b,:] = omega @ X.
__global__ __launch_bounds__(512, 8) void setformer_main(
    const float* __restrict__ neigh, const int* __restrict__ lengths,
    const unsigned short* __restrict__ MtBf,
    const float* __restrict__ wsv, float* __restrict__ yout)
{
    __shared__ unsigned short sX[64 * 128];   // bf16, XOR-swizzled (byte ^= (row&7)<<4)
    __shared__ unsigned short sG[64 * 128];   // bf16, same swizzle
    __shared__ float sWp[4][64];              // per-s-tile column-sum partials (omega parts)
    __shared__ float sW[64];                  // omega
    __shared__ float sY4[4][128];             // y partials over t-quarters

    const int tid  = threadIdx.x;
    const int lane = tid & 63;
    const int wv   = tid >> 6;    // wave 0..7
    const int l15  = lane & 15;
    const int lg   = lane >> 4;   // 0..3
    const int b    = blockIdx.x;

    // ---- Prefetch M B-fragments (tile dt=wv) + wadd (L2-hot, independent). ----
    const char* bB = (const char*)MtBf + (wv*16 + l15) * 256;
    bf16x8 bfr0 = *(const bf16x8*)(bB +   0 + lg*16);
    bf16x8 bfr1 = *(const bf16x8*)(bB +  64 + lg*16);
    bf16x8 bfr2 = *(const bf16x8*)(bB + 128 + lg*16);
    bf16x8 bfr3 = *(const bf16x8*)(bB + 192 + lg*16);
    const float wadd = wsv[wv*16 + l15];

    // ---- Staging: row 0-15 load issues before lengths; rows 16-63 issue
    //      back-to-back right after L arrives (one exposed round-trip).
    const float4* np4 = (const float4*)(neigh + (size_t)b * 8192);
    const float4 f0 = np4[tid];               // rows 0..15, always maybe-needed

    int L = lengths[b];
    L = max(1, min(64, L));
    const int ST = (L + 15) >> 4;             // 16-row tiles actually needed
    const int rr = tid >> 5, c4 = tid & 31;   // rr in 0..15

    float4 f1 = {0,0,0,0}, f2 = {0,0,0,0}, f3 = {0,0,0,0};
    if (rr + 16 < L) f1 = np4[tid + 512];     // all three issued together
    if (rr + 32 < L) f2 = np4[tid + 1024];
    if (rr + 48 < L) f3 = np4[tid + 1536];

    if (tid < 256) ((float*)sWp)[tid] = 0.f;

    {
        uint2 v = {0u, 0u};
        if (rr < L) { v.x = cvt_pk_bf16(f0.x, f0.y); v.y = cvt_pk_bf16(f0.z, f0.w); }
        *(uint2*)((char*)sX + rr*256 + ((c4*8) ^ ((rr & 7) << 4))) = v;
        if (ST > 1) {
            const int r = rr + 16;
            uint2 w = {0u, 0u};
            if (r < L) { w.x = cvt_pk_bf16(f1.x, f1.y); w.y = cvt_pk_bf16(f1.z, f1.w); }
            *(uint2*)((char*)sX + r*256 + ((c4*8) ^ ((r & 7) << 4))) = w;
        }
        if (ST > 2) {
            const int r = rr + 32;
            uint2 w = {0u, 0u};
            if (r < L) { w.x = cvt_pk_bf16(f2.x, f2.y); w.y = cvt_pk_bf16(f2.z, f2.w); }
            *(uint2*)((char*)sX + r*256 + ((c4*8) ^ ((r & 7) << 4))) = w;
        }
        if (ST > 3) {
            const int r = rr + 48;
            uint2 w = {0u, 0u};
            if (r < L) { w.x = cvt_pk_bf16(f3.x, f3.y); w.y = cvt_pk_bf16(f3.z, f3.w); }
            *(uint2*)((char*)sX + r*256 + ((c4*8) ^ ((r & 7) << 4))) = w;
        }
    }
    __syncthreads();

    // ---- Phase 2: G(:, dt=wv) = X @ M(:, wv-tile) + w, bf16 into sG ----
    for (int st = 0; st < ST; ++st) {
        const char* aB = (const char*)sX + (st*16 + l15) * 256;
        f32x4 acc = {0.f, 0.f, 0.f, 0.f};
        bf16x8 a0 = *(const bf16x8*)(aB + ((  0 + lg*16) ^ ((l15 & 7) << 4)));
        acc = __builtin_amdgcn_mfma_f32_16x16x32_bf16(a0, bfr0, acc, 0, 0, 0);
        bf16x8 a1 = *(const bf16x8*)(aB + (( 64 + lg*16) ^ ((l15 & 7) << 4)));
        acc = __builtin_amdgcn_mfma_f32_16x16x32_bf16(a1, bfr1, acc, 0, 0, 0);
        bf16x8 a2 = *(const bf16x8*)(aB + ((128 + lg*16) ^ ((l15 & 7) << 4)));
        acc = __builtin_amdgcn_mfma_f32_16x16x32_bf16(a2, bfr2, acc, 0, 0, 0);
        bf16x8 a3 = *(const bf16x8*)(aB + ((192 + lg*16) ^ ((l15 & 7) << 4)));
        acc = __builtin_amdgcn_mfma_f32_16x16x32_bf16(a3, bfr3, acc, 0, 0, 0);
        // D layout: row = lg*4+j, col = l15  (m89-verified)
        #pragma unroll
        for (int j = 0; j < 4; ++j) {
            const int gr  = st*16 + lg*4 + j;
            const int gcb = ((wv*16 + l15) * 2) ^ ((gr & 7) << 4);
            const float g = acc[j] + wadd;
            *(unsigned short*)((char*)sG + gr*256 + gcb) =
                (unsigned short)cvt_pk_bf16(g, g);
        }
    }
    __syncthreads();

    // ---- Phase 3: scores = G @ X^T, no-max softmax (scores ~N(0,1): global
    //      max ~5.5 sigma << fp32 exp overflow), column sums -> omega parts ----
    if (wv < ST) {
        const char* aB = (const char*)sG + (wv*16 + l15) * 256;
        bf16x8 afr[4];
        #pragma unroll
        for (int kk = 0; kk < 4; ++kk)
            afr[kk] = *(const bf16x8*)(aB + ((kk*64 + lg*16) ^ ((l15 & 7) << 4)));

        f32x4 sc[4];
        #pragma unroll
        for (int tt = 0; tt < 4; ++tt) {
            f32x4 acc = {0.f, 0.f, 0.f, 0.f};
            if (tt < ST) {
                const char* bBt = (const char*)sX + (tt*16 + l15) * 256;
                #pragma unroll
                for (int kk = 0; kk < 4; ++kk) {
                    bf16x8 bfr = *(const bf16x8*)(bBt + ((kk*64 + lg*16) ^ ((l15 & 7) << 4)));
                    acc = __builtin_amdgcn_mfma_f32_16x16x32_bf16(afr[kk], bfr, acc, 0, 0, 0);
                }
            }
            sc[tt] = acc;
        }

        // rows handled by this lane: s = wv*16 + lg*4 + j ; cols: t = tt*16 + l15
        float den[4] = {0.f, 0.f, 0.f, 0.f};
        #pragma unroll
        for (int tt = 0; tt < 4; ++tt) {
            if (tt < ST) {
                const bool tv = (tt*16 + l15) < L;
                #pragma unroll
                for (int j = 0; j < 4; ++j) {
                    float p = tv ? __expf(sc[tt][j]) : 0.f;
                    sc[tt][j] = p;
                    den[j] += p;
                }
            }
        }
        #pragma unroll
        for (int j = 0; j < 4; ++j) {
            #pragma unroll
            for (int off = 1; off < 16; off <<= 1)
                den[j] += __shfl_xor(den[j], off);
        }
        const float invL = 1.0f / (float)L;
        float rinv[4];
        #pragma unroll
        for (int j = 0; j < 4; ++j) {
            const int srow = wv*16 + lg*4 + j;
            rinv[j] = (srow < L) ? (invL / den[j]) : 0.f;   // 1/L folded -> omega directly
        }
        #pragma unroll
        for (int tt = 0; tt < 4; ++tt) {
            if (tt < ST) {
                float cp = sc[tt][0]*rinv[0] + sc[tt][1]*rinv[1]
                         + sc[tt][2]*rinv[2] + sc[tt][3]*rinv[3];
                cp += __shfl_xor(cp, 16);
                cp += __shfl_xor(cp, 32);
                if (lane < 16) sWp[wv][tt*16 + lane] = cp;
            }
        }
    }
    __syncthreads();

    // ---- omega -> sW ----
    if (tid < 64)
        sW[tid] = sWp[0][tid] + sWp[1][tid] + sWp[2][tid] + sWp[3][tid];
    __syncthreads();

    // ---- y = omega @ X, split 4-way over t across 512 threads ----
    {
        const int q = tid >> 7, col = tid & 127;
        float acc = 0.f;
        const int t0 = q * 16, t1 = min(t0 + 16, L);
        for (int t = t0; t < t1; ++t) {
            const unsigned short xv = *(const unsigned short*)
                ((const char*)sX + t*256 + ((col*2) ^ ((t & 7) << 4)));
            acc = fmaf(sW[t], bf2f(xv), acc);
        }
        sY4[q][col] = acc;
    }
    __syncthreads();

    if (tid < 128)
        yout[(size_t)b*128 + tid] = sY4[0][tid] + sY4[1][tid]
                                  + sY4[2][tid] + sY4[3][tid];
}

// out = Y @ N + c : batched 16-row GEMM; N read once per 16 sets (32MB L2 total).
__global__ __launch_bounds__(256) void setformer_out(
    const float* __restrict__ yin, const float* __restrict__ Nmat,
    const float* __restrict__ cvec, float* __restrict__ out)
{
    __shared__ float sy[16 * 128];
    const int tid = threadIdx.x;
    const size_t r0 = (size_t)blockIdx.x * 16;
    const float4* y4 = (const float4*)(yin + r0 * 128);
    float4* sy4 = (float4*)sy;
    sy4[tid]       = y4[tid];
    sy4[tid + 256] = y4[tid + 256];
    __syncthreads();
    const int col = tid & 127;
    const int rg  = (tid >> 7) * 8;           // rows rg..rg+7 of this 16-row tile
    float acc[8];
    #pragma unroll
    for (int i = 0; i < 8; ++i) acc[i] = 0.f;
    for (int d = 0; d < 128; d += 2) {
        const float n0 = Nmat[(d+0)*128 + col];
        const float n1 = Nmat[(d+1)*128 + col];
        #pragma unroll
        for (int i = 0; i < 8; ++i) {
            const float2 yv = *(const float2*)&sy[(rg + i)*128 + d];  // LDS broadcast
            acc[i] = fmaf(yv.x, n0, acc[i]);
            acc[i] = fmaf(yv.y, n1, acc[i]);
        }
    }
    const float c = cvec[col];
    #pragma unroll
    for (int i = 0; i < 8; ++i)
        out[(r0 + rg + i)*128 + col] = acc[i] + c;
}

extern "C" void kernel_launch(void* const* d_in, const int* in_sizes, int n_in,
                              void* d_out, int out_size, void* d_ws, size_t ws_size,
                              hipStream_t stream)
{
    const float* neigh   = (const float*)d_in[0];
    const int*   lengths = (const int*)  d_in[1];
    const float* Wq = (const float*)d_in[2];
    const float* bq = (const float*)d_in[3];
    const float* Wk = (const float*)d_in[4];
    // d_in[5] = bk: cancels in softmax (row-constant) -- unused.
    const float* Wv = (const float*)d_in[6];
    const float* bv = (const float*)d_in[7];
    const float* Wo = (const float*)d_in[8];
    const float* bo = (const float*)d_in[9];

    const int B = in_sizes[1];   // 8192

    char* ws = (char*)d_ws;
    unsigned short* MtBf = (unsigned short*)(ws);                 // 32768 B
    float* Nmat = (float*)(ws + 32768);                           // 65536 B
    float* wsv  = (float*)(ws + 32768 + 65536);                   // 512 B
    float* cvec = (float*)(ws + 32768 + 65536 + 512);             // 512 B
    float* ybuf = (float*)(ws + 32768 + 65536 + 1024);            // B*128*4 B

    hipLaunchKernelGGL(setformer_pre, dim3(128), dim3(256), 0, stream,
                       Wq, Wk, Wv, Wo, bq, bv, bo, MtBf, Nmat, wsv, cvec);
    hipLaunchKernelGGL(setformer_main, dim3(B), dim3(512), 0, stream,
                       neigh, lengths, MtBf, wsv, ybuf);
    hipLaunchKernelGGL(setformer_out, dim3(B / 16), dim3(256), 0, stream,
                       ybuf, Nmat, cvec, (float*)d_out);
}